// Round 2
// baseline (437.849 us; speedup 1.0000x reference)
//
#include <hip/hip_runtime.h>
#include <math.h>

// AttentionDecoder: score = (Wk^T (Wq [cur;ctx])) . cand_i over N=200000 rows,
// masked softmax, top-50 threshold filter, renormalize, log, and bit-exact
// replication of jax.random.categorical(key(42)) via threefry2x32 gumbel argmax.
// RNG uses the PARTITIONABLE threefry scheme (JAX default since 0.4.36):
// counter = 64-bit flat index -> (hi,lo) words, bits = out0 ^ out1.

#define CAP 4096  // candidate buffer for top-bin entries (expected ~50-300)

// ---- order-preserving float<->uint mapping (monotone increasing) ----
__device__ __forceinline__ unsigned int f2ord(float f){
  unsigned int b = __float_as_uint(f);
  return (b & 0x80000000u) ? ~b : (b | 0x80000000u);
}
__device__ __forceinline__ float ord2f(unsigned int u){
  unsigned int b = (u & 0x80000000u) ? (u & 0x7fffffffu) : ~u;
  return __uint_as_float(b);
}

__device__ __forceinline__ unsigned int rotl32(unsigned int x, int d){
  return (x << d) | (x >> (32 - d));
}

// JAX partitionable threefry bits for key (0,42) = jax.random.key(42):
// x0 = idx>>32 (==0 here), x1 = idx&0xffffffff; output = word0 ^ word1.
// gumbel = -log(-log(uniform)), uniform = bitcast((bits>>9)|0x3f800000)-1,
// clamped to float32 tiny (minval).
__device__ float gumbel_from_idx(unsigned int idx){
  unsigned int x0 = 0u, x1 = idx;
  const unsigned int ks0 = 0u, ks1 = 42u;
  const unsigned int ks2 = 0u ^ 42u ^ 0x1BD11BDAu;
  x0 += ks0; x1 += ks1;
#define TF_RND(r) { x0 += x1; x1 = rotl32(x1, (r)); x1 ^= x0; }
  TF_RND(13) TF_RND(15) TF_RND(26) TF_RND(6)
  x0 += ks1; x1 += ks2 + 1u;
  TF_RND(17) TF_RND(29) TF_RND(16) TF_RND(24)
  x0 += ks2; x1 += ks0 + 2u;
  TF_RND(13) TF_RND(15) TF_RND(26) TF_RND(6)
  x0 += ks0; x1 += ks1 + 3u;
  TF_RND(17) TF_RND(29) TF_RND(16) TF_RND(24)
  x0 += ks1; x1 += ks2 + 4u;
  TF_RND(13) TF_RND(15) TF_RND(26) TF_RND(6)
  x0 += ks2; x1 += ks0 + 5u;
#undef TF_RND
  unsigned int bits = x0 ^ x1;
  unsigned int fb = (bits >> 9) | 0x3f800000u;   // [1,2)
  float f = __uint_as_float(fb) - 1.0f;          // [0,1), exact
  float u = (f < 1.17549435e-38f) ? 1.17549435e-38f : f;  // minval=tiny
  return -logf(-logf(u));
}

// scal layout (uint/float aliased): [0]=nbuf [1]=u_lo [2]=mprime [3]=Z [4]=s_thr [5]=denom
__global__ void k_prep(const float* __restrict__ cur, const float* __restrict__ ctx,
                       const float* __restrict__ Wq, const float* __restrict__ Wk,
                       float* __restrict__ v, unsigned int* __restrict__ hist,
                       unsigned int* __restrict__ scal_u){
  __shared__ float comb[256];
  __shared__ float q[128];
  int t = threadIdx.x;
  for (int k = t; k < 2048; k += 256) hist[k] = 0u;
  if (t < 8) scal_u[t] = 0u;
  comb[t] = (t < 128) ? cur[t] : ctx[t - 128];
  __syncthreads();
  if (t < 128){
    float acc = 0.f;
    const float* row = Wq + t * 256;
    for (int j = 0; j < 256; ++j) acc = fmaf(row[j], comb[j], acc);
    q[t] = acc;
  }
  __syncthreads();
  if (t < 128){
    float acc = 0.f;
    for (int h = 0; h < 128; ++h) acc = fmaf(q[h], Wk[h * 128 + t], acc);
    v[t] = acc;
  }
}

// wave-per-row dot products: lane l reads cand[r][2l..2l+1] as float2 (512B/row,
// coalesced). 8 rows per wave, 4 waves per block -> 32 rows/block.
__global__ void k_score(const float* __restrict__ cand, const int* __restrict__ mask,
                        const float* __restrict__ v, float* __restrict__ scores,
                        unsigned int* __restrict__ hist, int N){
  int wave = threadIdx.x >> 6;
  int lane = threadIdx.x & 63;
  float2 vv = ((const float2*)v)[lane];
  int base = (blockIdx.x * 4 + wave) * 8;
  float srow = 0.f;
  for (int k = 0; k < 8; ++k){
    int r = base + k;                       // wave-uniform
    float2 c = make_float2(0.f, 0.f);
    if (r < N) c = ((const float2*)(cand + (size_t)r * 128))[lane];
    float p = fmaf(c.x, vv.x, c.y * vv.y);
    for (int off = 32; off; off >>= 1) p += __shfl_xor(p, off, 64);
    if (lane == k) srow = p;                // lane k keeps row base+k's score
  }
  int r = base + lane;
  if (lane < 8 && r < N){
    int m = mask[r];
    float s = (m == 0) ? -__builtin_inff() : srow;
    scores[r] = s;
    if (m != 0) atomicAdd(&hist[f2ord(s) >> 21], 1u);
  }
}

// single block: suffix sums of 2048-bin histogram; pick b_sel = max bin with
// count(bins >= b_sel) >= ktop; mprime = lower edge of highest nonempty bin.
__global__ void k_scan(const unsigned int* __restrict__ hist,
                       unsigned int* __restrict__ scal_u, int ktop){
  __shared__ unsigned int suf[256];
  __shared__ int maxbin_sh;
  __shared__ int csel_sh;
  int t = threadIdx.x;
  unsigned int csum = 0; int localmax = -1;
  for (int k = 0; k < 8; ++k){
    unsigned int x = hist[t * 8 + k];
    csum += x;
    if (x) localmax = t * 8 + k;
  }
  suf[t] = csum;
  if (t == 0){ maxbin_sh = -1; csel_sh = -1; }
  __syncthreads();
  if (localmax >= 0) atomicMax(&maxbin_sh, localmax);
  for (int d = 1; d < 256; d <<= 1){
    unsigned int add = (t + d < 256) ? suf[t + d] : 0u;
    __syncthreads();
    suf[t] += add;
    __syncthreads();
  }
  unsigned int st = suf[t];
  unsigned int sn = (t < 255) ? suf[t + 1] : 0u;
  if (st >= (unsigned)ktop && sn < (unsigned)ktop) csel_sh = t;  // unique t
  __syncthreads();
  if (t == 0){
    int b_sel = 0;
    if (csel_sh >= 0){
      int c = csel_sh;
      unsigned int cum = (c < 255) ? suf[c + 1] : 0u;
      for (int b = 8 * c + 7; b >= 8 * c; --b){
        cum += hist[b];
        if (cum >= (unsigned)ktop){ b_sel = b; break; }
      }
    }
    scal_u[1] = ((unsigned int)b_sel) << 21;   // u_lo
    float mprime = -__builtin_inff();
    if (maxbin_sh >= 0) mprime = ord2f(((unsigned int)maxbin_sh) << 21);
    ((float*)scal_u)[2] = mprime;
  }
}

// collect all entries with u >= u_lo (superset of top-ktop) + accumulate Z.
__global__ void k_collect(const float* __restrict__ scores,
                          unsigned int* __restrict__ scal_u,
                          unsigned int* __restrict__ buf_idx,
                          float* __restrict__ buf_s, int N){
  int i = blockIdx.x * 256 + threadIdx.x;
  float* scal_f = (float*)scal_u;
  float mprime = scal_f[2];
  unsigned int u_lo = scal_u[1];
  float e = 0.f;
  if (i < N){
    float s = scores[i];
    e = expf(s - mprime);                         // s=-inf -> 0
    if (s == s && s > -__builtin_inff() && f2ord(s) >= u_lo){
      unsigned int pos = atomicAdd(&scal_u[0], 1u);
      if (pos < CAP){ buf_idx[pos] = (unsigned int)i; buf_s[pos] = s; }
    }
  }
  for (int off = 32; off; off >>= 1) e += __shfl_xor(e, off, 64);
  __shared__ float wsum[4];
  int wave = threadIdx.x >> 6, lane = threadIdx.x & 63;
  if (lane == 0) wsum[wave] = e;
  __syncthreads();
  if (threadIdx.x == 0) atomicAdd(&scal_f[3], wsum[0] + wsum[1] + wsum[2] + wsum[3]);
}

// single block: exact ktop-th largest among collected; denom; gumbel argmax.
__global__ void k_select(unsigned int* __restrict__ scal_u,
                         const unsigned int* __restrict__ buf_idx,
                         const float* __restrict__ buf_s,
                         float* __restrict__ out, int N, int ktop){
  __shared__ float s_lds[CAP];
  __shared__ float thr_sh;
  __shared__ float wred[4];
  __shared__ float rv[4], rl[4];
  __shared__ unsigned int ri[4];
  float* scal_f = (float*)scal_u;
  int t = threadIdx.x;
  int C = (int)scal_u[0]; if (C > CAP) C = CAP;
  for (int j = t; j < C; j += 256) s_lds[j] = buf_s[j];
  if (t == 0) thr_sh = -__builtin_inff();
  __syncthreads();
  if (C > ktop){
    for (int j = t; j < C; j += 256){
      float sj = s_lds[j];
      int g = 0, e = 0;
      for (int k2 = 0; k2 < C; ++k2){
        float sk = s_lds[k2];
        g += (sk > sj);
        e += (sk == sj);
      }
      if (g < ktop && g + e >= ktop) thr_sh = sj;  // all writers write same value
    }
  }
  __syncthreads();
  float s_thr = thr_sh;
  float mprime = scal_f[2];
  float Z = scal_f[3];
  // denom = sum of included probs + 1e-10
  float part = 0.f;
  for (int j = t; j < C; j += 256){
    float sj = s_lds[j];
    if (sj >= s_thr) part += expf(sj - mprime) / Z;
  }
  for (int off = 32; off; off >>= 1) part += __shfl_xor(part, off, 64);
  int wave = t >> 6, lane = t & 63;
  if (lane == 0) wred[wave] = part;
  __syncthreads();
  float denom = (wred[0] + wred[1] + wred[2] + wred[3]) + 1e-10f;
  if (t == 0){ scal_f[4] = s_thr; scal_f[5] = denom; }
  // categorical: argmax(logit + gumbel) over included, first-index tie-break
  float bestv = -__builtin_inff(), bestlogit = -__builtin_inff();
  unsigned int bestidx = 0xFFFFFFFFu;
  for (int j = t; j < C; j += 256){
    float sj = s_lds[j];
    if (sj >= s_thr){
      unsigned int idx = buf_idx[j];
      float p = expf(sj - mprime) / Z;
      float logit = logf(p / denom);
      float val = logit + gumbel_from_idx(idx);
      if (val > bestv || (val == bestv && idx < bestidx)){
        bestv = val; bestlogit = logit; bestidx = idx;
      }
    }
  }
  for (int off = 32; off; off >>= 1){
    float ov = __shfl_xor(bestv, off, 64);
    float ol = __shfl_xor(bestlogit, off, 64);
    unsigned int oi = (unsigned int)__shfl_xor((int)bestidx, off, 64);
    if (ov > bestv || (ov == bestv && oi < bestidx)){
      bestv = ov; bestlogit = ol; bestidx = oi;
    }
  }
  if (lane == 0){ rv[wave] = bestv; rl[wave] = bestlogit; ri[wave] = bestidx; }
  __syncthreads();
  if (t == 0){
    for (int w = 1; w < 4; ++w){
      if (rv[w] > rv[0] || (rv[w] == rv[0] && ri[w] < ri[0])){
        rv[0] = rv[w]; rl[0] = rl[w]; ri[0] = ri[w];
      }
    }
    out[N] = rl[0];               // log_prob_action
    out[N + 1] = (float)ri[0];    // action_idx (exact in f32, < 2^24)
  }
}

// rewrite scores in-place into log(filtered + 1e-10)
__global__ void k_final(float* __restrict__ out, const unsigned int* __restrict__ scal_u, int N){
  int i = blockIdx.x * 256 + threadIdx.x;
  if (i >= N) return;
  const float* scal_f = (const float*)scal_u;
  float mprime = scal_f[2];
  float Z = scal_f[3];
  float s_thr = scal_f[4];
  float denom = scal_f[5];
  float s = out[i];
  float filt = 0.f;
  if (s >= s_thr){                 // -inf (masked) naturally excluded
    float p = expf(s - mprime) / Z;
    filt = p / denom;
  }
  out[i] = logf(filt + 1e-10f);
}

extern "C" void kernel_launch(void* const* d_in, const int* in_sizes, int n_in,
                              void* d_out, int out_size, void* d_ws, size_t ws_size,
                              hipStream_t stream){
  const float* cur  = (const float*)d_in[0];
  const float* ctx  = (const float*)d_in[1];
  const float* cand = (const float*)d_in[2];
  const float* Wq   = (const float*)d_in[3];
  const float* Wk   = (const float*)d_in[4];
  const int*   mask = (const int*)d_in[5];
  int N = in_sizes[5];
  float* out = (float*)d_out;

  char* ws = (char*)d_ws;
  unsigned int* hist    = (unsigned int*)ws;               // 2048*4 = 8192 B
  float*        v       = (float*)(ws + 8192);             // 128*4  = 512 B
  unsigned int* scal_u  = (unsigned int*)(ws + 8704);      // 8*4    = 32 B (pad 64)
  unsigned int* buf_idx = (unsigned int*)(ws + 8768);      // CAP*4
  float*        buf_s   = (float*)(ws + 8768 + CAP * 4);   // CAP*4  (~42 KB total)

  int ktop = N / 2; if (ktop < 1) ktop = 1; if (ktop > 50) ktop = 50;

  k_prep<<<1, 256, 0, stream>>>(cur, ctx, Wq, Wk, v, hist, scal_u);
  k_score<<<(N + 31) / 32, 256, 0, stream>>>(cand, mask, v, out, hist, N);
  k_scan<<<1, 256, 0, stream>>>(hist, scal_u, ktop);
  k_collect<<<(N + 255) / 256, 256, 0, stream>>>(out, scal_u, buf_idx, buf_s, N);
  k_select<<<1, 256, 0, stream>>>(scal_u, buf_idx, buf_s, out, N, ktop);
  k_final<<<(N + 255) / 256, 256, 0, stream>>>(out, scal_u, N);
}

// Round 3
// 372.912 us; speedup vs baseline: 1.1741x; 1.1741x over previous
//
#include <hip/hip_runtime.h>
#include <math.h>

// AttentionDecoder: score_i = (Wk^T (Wq [cur;ctx])) . cand_i over N=200000,
// masked softmax -> top-50 threshold filter -> renormalize -> log, plus
// bit-exact jax.random.categorical(key(42)) via partitionable-threefry gumbel.
// 4 kernels: prep | score(+Z+hist+scan-in-last-block) | collect(+select) | final.

#define CAP 4096
#define NEG_INF (-__builtin_inff())

// order-preserving float->uint mapping (monotone increasing)
__device__ __forceinline__ unsigned int f2ord(float f){
  unsigned int b = __float_as_uint(f);
  return (b & 0x80000000u) ? ~b : (b | 0x80000000u);
}
__device__ __forceinline__ unsigned int rotl32(unsigned int x, int d){
  return (x << d) | (x >> (32 - d));
}

// JAX partitionable threefry, key (0,42): x0=idx>>32(=0), x1=idx; bits=w0^w1.
// gumbel = -log(-log(u)), u = bitcast((bits>>9)|0x3f800000)-1 clamped to tiny.
__device__ float gumbel_from_idx(unsigned int idx){
  unsigned int x0 = 0u, x1 = idx;
  const unsigned int ks0 = 0u, ks1 = 42u;
  const unsigned int ks2 = 0u ^ 42u ^ 0x1BD11BDAu;
  x0 += ks0; x1 += ks1;
#define TF_RND(r) { x0 += x1; x1 = rotl32(x1, (r)); x1 ^= x0; }
  TF_RND(13) TF_RND(15) TF_RND(26) TF_RND(6)
  x0 += ks1; x1 += ks2 + 1u;
  TF_RND(17) TF_RND(29) TF_RND(16) TF_RND(24)
  x0 += ks2; x1 += ks0 + 2u;
  TF_RND(13) TF_RND(15) TF_RND(26) TF_RND(6)
  x0 += ks0; x1 += ks1 + 3u;
  TF_RND(17) TF_RND(29) TF_RND(16) TF_RND(24)
  x0 += ks1; x1 += ks2 + 4u;
  TF_RND(13) TF_RND(15) TF_RND(26) TF_RND(6)
  x0 += ks2; x1 += ks0 + 5u;
#undef TF_RND
  unsigned int bits = x0 ^ x1;
  unsigned int fb = (bits >> 9) | 0x3f800000u;
  float f = __uint_as_float(fb) - 1.0f;
  float u = (f < 1.17549435e-38f) ? 1.17549435e-38f : f;
  return -logf(-logf(u));
}

// scal layout (uint/float aliased):
// [0]=nbuf [1]=u_lo [3]=Z [4]=s_thr [5]=lnD [6]=done_score [7]=done_collect
__global__ void k_prep(const float* __restrict__ cur, const float* __restrict__ ctx,
                       const float* __restrict__ Wq, const float* __restrict__ Wk,
                       float* __restrict__ v, unsigned int* __restrict__ hist,
                       unsigned int* __restrict__ scal_u){
  __shared__ float comb[256];
  __shared__ float q[128];
  int t = threadIdx.x;
  for (int k = t; k < 2048; k += 256) hist[k] = 0u;
  if (t < 8) scal_u[t] = 0u;
  comb[t] = (t < 128) ? cur[t] : ctx[t - 128];
  __syncthreads();
  if (t < 128){
    float acc = 0.f;
    const float* row = Wq + t * 256;
    for (int j = 0; j < 256; ++j) acc = fmaf(row[j], comb[j], acc);
    q[t] = acc;
  }
  __syncthreads();
  if (t < 128){
    float acc = 0.f;
    for (int h = 0; h < 128; ++h) acc = fmaf(q[h], Wk[h * 128 + t], acc);
    v[t] = acc;
  }
}

// Half-wave per row, float4 coalesced (1KB/wave-instr), 16 rows/wave.
// 8 independent loads in flight, 8 independent 5-shfl reduce chains.
// Z = sum(exp(s)) accumulated here; last block runs the histogram scan.
__global__ __launch_bounds__(256) void k_score(const float* __restrict__ cand,
    const int* __restrict__ mask, const float* __restrict__ v,
    float* __restrict__ scores, unsigned int* __restrict__ hist,
    unsigned int* __restrict__ scal_u, int N, int ktop){
  int t = threadIdx.x;
  int lane = t & 63, wave = t >> 6;
  int hi = lane >> 5, hl = lane & 31;
  float4 v4 = ((const float4*)v)[hl];
  int base = (blockIdx.x * 4 + wave) * 16;
  const float4* cp = (const float4*)cand;
  float p[8];
  #pragma unroll
  for (int k = 0; k < 8; ++k){
    int r = base + 2 * k + hi;
    float4 c = make_float4(0.f, 0.f, 0.f, 0.f);
    if (r < N) c = cp[(size_t)r * 32 + hl];     // lanes 0-31: row r contiguous
    p[k] = fmaf(c.x, v4.x, fmaf(c.y, v4.y, fmaf(c.z, v4.z, c.w * v4.w)));
  }
  #pragma unroll
  for (int k = 0; k < 8; ++k){                   // 8 independent chains (ILP)
    p[k] += __shfl_xor(p[k], 1, 64);
    p[k] += __shfl_xor(p[k], 2, 64);
    p[k] += __shfl_xor(p[k], 4, 64);
    p[k] += __shfl_xor(p[k], 8, 64);
    p[k] += __shfl_xor(p[k], 16, 64);            // now half-wave holds row sum
  }
  float sv = p[0];
  #pragma unroll
  for (int k = 1; k < 8; ++k) sv = (hl == k) ? p[k] : sv;  // cndmask chain
  float ez = 0.f;
  if (hl < 8){                                   // writer lanes: hi*32+k -> row base+2k+hi
    int r = base + 2 * hl + hi;
    if (r < N){
      int m = mask[r];
      float s = m ? sv : NEG_INF;
      scores[r] = s;
      if (m){
        atomicAdd(&hist[f2ord(s) >> 21], 1u);
        ez = expf(s);                            // |s| bounded ~58 -> no overflow
      }
    }
  }
  #pragma unroll
  for (int off = 32; off; off >>= 1) ez += __shfl_xor(ez, off, 64);
  __shared__ float wsum[4];
  __shared__ int is_last;
  if (lane == 0) wsum[wave] = ez;
  __syncthreads();
  if (t == 0){
    atomicAdd((float*)scal_u + 3, wsum[0] + wsum[1] + wsum[2] + wsum[3]);
    __threadfence();
    unsigned int old = atomicAdd(&scal_u[6], 1u);
    is_last = (old == gridDim.x - 1u);
  }
  __syncthreads();
  if (!is_last) return;
  __threadfence();                               // acquire: see all hist atomics
  // ---- histogram suffix scan -> u_lo (bin lower edge of ktop-th score) ----
  __shared__ unsigned int suf[256];
  __shared__ int csel_sh;
  unsigned int csum = 0;
  for (int k = 0; k < 8; ++k) csum += hist[t * 8 + k];
  suf[t] = csum;
  if (t == 0) csel_sh = -1;
  __syncthreads();
  for (int d = 1; d < 256; d <<= 1){
    unsigned int add = (t + d < 256) ? suf[t + d] : 0u;
    __syncthreads();
    suf[t] += add;
    __syncthreads();
  }
  unsigned int st = suf[t];
  unsigned int sn = (t < 255) ? suf[t + 1] : 0u;
  if (st >= (unsigned)ktop && sn < (unsigned)ktop) csel_sh = t;   // unique
  __syncthreads();
  if (t == 0){
    int b_sel = 0;
    if (csel_sh >= 0){
      int c = csel_sh;
      unsigned int cum = (c < 255) ? suf[c + 1] : 0u;
      for (int b = 8 * c + 7; b >= 8 * c; --b){
        cum += hist[b];
        if (cum >= (unsigned)ktop){ b_sel = b; break; }
      }
    }
    scal_u[1] = ((unsigned int)b_sel) << 21;
  }
}

// Collect entries >= bin edge (superset of top-ktop); last block does exact
// rank-select, denom, and gumbel-argmax categorical.
__global__ __launch_bounds__(256) void k_collect(const float* __restrict__ scores,
    unsigned int* __restrict__ scal_u, unsigned int* __restrict__ buf_idx,
    float* __restrict__ buf_s, float* __restrict__ out, int N, int ktop){
  int t = threadIdx.x;
  unsigned int u_lo = scal_u[1];
  int i0 = (blockIdx.x * 256 + t) * 4;
  if (i0 + 3 < N){
    float4 s4 = *(const float4*)(scores + i0);
    float ss[4] = {s4.x, s4.y, s4.z, s4.w};
    #pragma unroll
    for (int e = 0; e < 4; ++e){
      float s = ss[e];
      if (s > NEG_INF && f2ord(s) >= u_lo){
        unsigned int pos = atomicAdd(&scal_u[0], 1u);
        if (pos < CAP){ buf_idx[pos] = (unsigned int)(i0 + e); buf_s[pos] = s; }
      }
    }
  } else {
    for (int e = 0; e < 4; ++e){
      int i = i0 + e;
      if (i < N){
        float s = scores[i];
        if (s > NEG_INF && f2ord(s) >= u_lo){
          unsigned int pos = atomicAdd(&scal_u[0], 1u);
          if (pos < CAP){ buf_idx[pos] = (unsigned int)i; buf_s[pos] = s; }
        }
      }
    }
  }
  __syncthreads();
  __shared__ int is_last;
  if (t == 0){
    __threadfence();
    unsigned int old = atomicAdd(&scal_u[7], 1u);
    is_last = (old == gridDim.x - 1u);
  }
  __syncthreads();
  if (!is_last) return;
  __threadfence();
  // ---- exact select + categorical ----
  float* scal_f = (float*)scal_u;
  __shared__ float s_lds[CAP];
  __shared__ float thr_sh;
  __shared__ float wred[4];
  __shared__ float rv[4], rl[4];
  __shared__ unsigned int ri[4];
  int C = (int)scal_u[0]; if (C > CAP) C = CAP;
  for (int j = t; j < C; j += 256) s_lds[j] = buf_s[j];
  if (t == 0) thr_sh = NEG_INF;
  __syncthreads();
  if (C > ktop){
    for (int j = t; j < C; j += 256){
      float sj = s_lds[j];
      int g = 0, e = 0;
      for (int k2 = 0; k2 < C; ++k2){
        float sk = s_lds[k2];
        g += (sk > sj);
        e += (sk == sj);
      }
      if (g < ktop && g + e >= ktop) thr_sh = sj;   // all writers same value
    }
  }
  __syncthreads();
  float s_thr = thr_sh;
  float Z = scal_f[3];
  float part = 0.f;
  for (int j = t; j < C; j += 256){
    float sj = s_lds[j];
    if (sj >= s_thr) part += expf(sj);
  }
  #pragma unroll
  for (int off = 32; off; off >>= 1) part += __shfl_xor(part, off, 64);
  int wave = t >> 6, lane = t & 63;
  if (lane == 0) wred[wave] = part;
  __syncthreads();
  float T = wred[0] + wred[1] + wred[2] + wred[3];
  float D = T + 1e-10f * Z;                 // = Z*(sum_top p + 1e-10)
  float lnD = logf(D);
  if (t == 0){ scal_f[4] = s_thr; scal_f[5] = lnD; }
  float bestv = NEG_INF, bestlogit = NEG_INF;
  unsigned int bestidx = 0xFFFFFFFFu;
  for (int j = t; j < C; j += 256){
    float sj = s_lds[j];
    if (sj >= s_thr){
      unsigned int idx = buf_idx[j];
      float logit = sj - lnD;               // log(filtered)
      float val = logit + gumbel_from_idx(idx);
      if (val > bestv || (val == bestv && idx < bestidx)){
        bestv = val; bestlogit = logit; bestidx = idx;
      }
    }
  }
  #pragma unroll
  for (int off = 32; off; off >>= 1){
    float ov = __shfl_xor(bestv, off, 64);
    float ol = __shfl_xor(bestlogit, off, 64);
    unsigned int oi = (unsigned int)__shfl_xor((int)bestidx, off, 64);
    if (ov > bestv || (ov == bestv && oi < bestidx)){
      bestv = ov; bestlogit = ol; bestidx = oi;
    }
  }
  if (lane == 0){ rv[wave] = bestv; rl[wave] = bestlogit; ri[wave] = bestidx; }
  __syncthreads();
  if (t == 0){
    for (int w = 1; w < 4; ++w){
      if (rv[w] > rv[0] || (rv[w] == rv[0] && ri[w] < ri[0])){
        rv[0] = rv[w]; rl[0] = rl[w]; ri[0] = ri[w];
      }
    }
    out[N] = rl[0];                 // log_prob_action
    out[N + 1] = (float)ri[0];      // action_idx
  }
}

// rewrite scores in-place into log(filtered + 1e-10)
__global__ __launch_bounds__(256) void k_final(float* __restrict__ out,
    const unsigned int* __restrict__ scal_u, int N){
  const float* scal_f = (const float*)scal_u;
  float s_thr = scal_f[4];
  float lnD = scal_f[5];
  const float NLOG = logf(1e-10f);
  int i0 = (blockIdx.x * 256 + threadIdx.x) * 4;
  if (i0 + 3 < N){
    float4 s4 = *(const float4*)(out + i0);
    float4 r;
    r.x = (s4.x >= s_thr) ? logf(expf(s4.x - lnD) + 1e-10f) : NLOG;
    r.y = (s4.y >= s_thr) ? logf(expf(s4.y - lnD) + 1e-10f) : NLOG;
    r.z = (s4.z >= s_thr) ? logf(expf(s4.z - lnD) + 1e-10f) : NLOG;
    r.w = (s4.w >= s_thr) ? logf(expf(s4.w - lnD) + 1e-10f) : NLOG;
    *(float4*)(out + i0) = r;
  } else {
    for (int e = 0; e < 4; ++e){
      int i = i0 + e;
      if (i < N){
        float s = out[i];
        out[i] = (s >= s_thr) ? logf(expf(s - lnD) + 1e-10f) : NLOG;
      }
    }
  }
}

extern "C" void kernel_launch(void* const* d_in, const int* in_sizes, int n_in,
                              void* d_out, int out_size, void* d_ws, size_t ws_size,
                              hipStream_t stream){
  const float* cur  = (const float*)d_in[0];
  const float* ctx  = (const float*)d_in[1];
  const float* cand = (const float*)d_in[2];
  const float* Wq   = (const float*)d_in[3];
  const float* Wk   = (const float*)d_in[4];
  const int*   mask = (const int*)d_in[5];
  int N = in_sizes[5];
  float* out = (float*)d_out;

  char* ws = (char*)d_ws;
  unsigned int* hist    = (unsigned int*)ws;                    // 8192 B
  float*        v       = (float*)(ws + 8192);                  // 512 B
  unsigned int* scal_u  = (unsigned int*)(ws + 8704);           // 32 B (pad 64)
  unsigned int* buf_idx = (unsigned int*)(ws + 8768);           // CAP*4
  float*        buf_s   = (float*)(ws + 8768 + CAP * 4);        // CAP*4

  int ktop = N / 2; if (ktop < 1) ktop = 1; if (ktop > 50) ktop = 50;

  int g_score = (N + 63) / 64;       // 64 rows per block (16/wave x 4 waves)
  int g_pass  = (N + 1023) / 1024;   // 4 elems/thread

  k_prep<<<1, 256, 0, stream>>>(cur, ctx, Wq, Wk, v, hist, scal_u);
  k_score<<<g_score, 256, 0, stream>>>(cand, mask, v, out, hist, scal_u, N, ktop);
  k_collect<<<g_pass, 256, 0, stream>>>(out, scal_u, buf_idx, buf_s, out, N, ktop);
  k_final<<<g_pass, 256, 0, stream>>>(out, scal_u, N);
}

// Round 4
// 219.859 us; speedup vs baseline: 1.9915x; 1.6961x over previous
//
#include <hip/hip_runtime.h>
#include <math.h>

// AttentionDecoder: score_i = (Wk^T (Wq [cur;ctx])) . cand_i over N=200000,
// masked softmax -> top-50 threshold filter -> renormalize -> log, plus
// bit-exact jax.random.categorical(key(42)) via partitionable-threefry gumbel.
// 4 kernels: prep | score(LDS-hist + Z, scan in last block) | collect(+select) | final.
// R4 change: histogram aggregated in LDS per block, flushed once per nonzero bin
// (kills the ~7k same-address global-atomic serialization that made R3 215us).

#define CAP 4096
#define NEG_INF (-__builtin_inff())
#define SCORE_BLOCKS 512

// order-preserving float->uint mapping (monotone increasing)
__device__ __forceinline__ unsigned int f2ord(float f){
  unsigned int b = __float_as_uint(f);
  return (b & 0x80000000u) ? ~b : (b | 0x80000000u);
}
__device__ __forceinline__ unsigned int rotl32(unsigned int x, int d){
  return (x << d) | (x >> (32 - d));
}

// JAX partitionable threefry, key (0,42): x0=idx>>32(=0), x1=idx; bits=w0^w1.
// gumbel = -log(-log(u)), u = bitcast((bits>>9)|0x3f800000)-1 clamped to tiny.
__device__ float gumbel_from_idx(unsigned int idx){
  unsigned int x0 = 0u, x1 = idx;
  const unsigned int ks0 = 0u, ks1 = 42u;
  const unsigned int ks2 = 0u ^ 42u ^ 0x1BD11BDAu;
  x0 += ks0; x1 += ks1;
#define TF_RND(r) { x0 += x1; x1 = rotl32(x1, (r)); x1 ^= x0; }
  TF_RND(13) TF_RND(15) TF_RND(26) TF_RND(6)
  x0 += ks1; x1 += ks2 + 1u;
  TF_RND(17) TF_RND(29) TF_RND(16) TF_RND(24)
  x0 += ks2; x1 += ks0 + 2u;
  TF_RND(13) TF_RND(15) TF_RND(26) TF_RND(6)
  x0 += ks0; x1 += ks1 + 3u;
  TF_RND(17) TF_RND(29) TF_RND(16) TF_RND(24)
  x0 += ks1; x1 += ks2 + 4u;
  TF_RND(13) TF_RND(15) TF_RND(26) TF_RND(6)
  x0 += ks2; x1 += ks0 + 5u;
#undef TF_RND
  unsigned int bits = x0 ^ x1;
  unsigned int fb = (bits >> 9) | 0x3f800000u;
  float f = __uint_as_float(fb) - 1.0f;
  float u = (f < 1.17549435e-38f) ? 1.17549435e-38f : f;
  return -logf(-logf(u));
}

// scal layout (uint/float aliased):
// [0]=nbuf [1]=u_lo [3]=Z [4]=s_thr [5]=lnD [6]=done_score [7]=done_collect
__global__ void k_prep(const float* __restrict__ cur, const float* __restrict__ ctx,
                       const float* __restrict__ Wq, const float* __restrict__ Wk,
                       float* __restrict__ v, unsigned int* __restrict__ hist,
                       unsigned int* __restrict__ scal_u){
  __shared__ float comb[256];
  __shared__ float q[128];
  int t = threadIdx.x;
  for (int k = t; k < 2048; k += 256) hist[k] = 0u;
  if (t < 8) scal_u[t] = 0u;
  comb[t] = (t < 128) ? cur[t] : ctx[t - 128];
  __syncthreads();
  if (t < 128){
    float acc = 0.f;
    const float* row = Wq + t * 256;
    for (int j = 0; j < 256; ++j) acc = fmaf(row[j], comb[j], acc);
    q[t] = acc;
  }
  __syncthreads();
  if (t < 128){
    float acc = 0.f;
    for (int h = 0; h < 128; ++h) acc = fmaf(q[h], Wk[h * 128 + t], acc);
    v[t] = acc;
  }
}

// Half-wave per row, float4 coalesced; 16 rows/wave/tile; grid-stride tiles.
// Histogram in LDS, flushed once per block. Z accumulated per block.
// Last block runs the histogram suffix scan.
__global__ __launch_bounds__(256) void k_score(const float* __restrict__ cand,
    const int* __restrict__ mask, const float* __restrict__ v,
    float* __restrict__ scores, unsigned int* __restrict__ hist,
    unsigned int* __restrict__ scal_u, int N, int ktop){
  __shared__ unsigned int lhist[2048];
  __shared__ float wsum[4];
  __shared__ int is_last;
  int t = threadIdx.x;
  int lane = t & 63, wave = t >> 6;
  int hi = lane >> 5, hl = lane & 31;
  for (int k = t; k < 2048; k += 256) lhist[k] = 0u;
  __syncthreads();
  float4 v4 = ((const float4*)v)[hl];
  const float4* cp = (const float4*)cand;
  float ezacc = 0.f;
  int ntiles = (N + 63) / 64;
  for (int tile = blockIdx.x; tile < ntiles; tile += gridDim.x){
    int base = tile * 64 + wave * 16;
    float p[8];
    #pragma unroll
    for (int k = 0; k < 8; ++k){
      int r = base + 2 * k + hi;
      float4 c = make_float4(0.f, 0.f, 0.f, 0.f);
      if (r < N) c = cp[(size_t)r * 32 + hl];   // half-wave: row contiguous
      p[k] = fmaf(c.x, v4.x, fmaf(c.y, v4.y, fmaf(c.z, v4.z, c.w * v4.w)));
    }
    #pragma unroll
    for (int k = 0; k < 8; ++k){                // 8 independent chains (ILP)
      p[k] += __shfl_xor(p[k], 1, 64);
      p[k] += __shfl_xor(p[k], 2, 64);
      p[k] += __shfl_xor(p[k], 4, 64);
      p[k] += __shfl_xor(p[k], 8, 64);
      p[k] += __shfl_xor(p[k], 16, 64);
    }
    float sv = p[0];
    #pragma unroll
    for (int k = 1; k < 8; ++k) sv = (hl == k) ? p[k] : sv;
    if (hl < 8){                                // writer lanes
      int r = base + 2 * hl + hi;
      if (r < N){
        int m = mask[r];
        float s = m ? sv : NEG_INF;
        scores[r] = s;
        if (m){
          atomicAdd(&lhist[f2ord(s) >> 21], 1u);   // LDS atomic: cheap
          ezacc += expf(s);                        // |s| bounded -> no overflow
        }
      }
    }
  }
  #pragma unroll
  for (int off = 32; off; off >>= 1) ezacc += __shfl_xor(ezacc, off, 64);
  if (lane == 0) wsum[wave] = ezacc;
  __syncthreads();
  // flush nonzero LDS bins to global histogram (<=1 atomic/bin/block)
  for (int k = t; k < 2048; k += 256){
    unsigned int c = lhist[k];
    if (c) atomicAdd(&hist[k], c);
  }
  if (t == 0) atomicAdd((float*)scal_u + 3, wsum[0] + wsum[1] + wsum[2] + wsum[3]);
  __syncthreads();                     // all block's atomics drained (waitcnt before barrier)
  if (t == 0){
    __threadfence();
    unsigned int old = atomicAdd(&scal_u[6], 1u);
    is_last = (old == gridDim.x - 1u);
  }
  __syncthreads();
  if (!is_last) return;
  __threadfence();                     // acquire: see all hist flushes
  // ---- histogram suffix scan -> u_lo (bin lower edge of ktop-th score) ----
  __shared__ unsigned int suf[256];
  __shared__ int csel_sh;
  unsigned int csum = 0;
  for (int k = 0; k < 8; ++k) csum += hist[t * 8 + k];
  suf[t] = csum;
  if (t == 0) csel_sh = -1;
  __syncthreads();
  for (int d = 1; d < 256; d <<= 1){
    unsigned int add = (t + d < 256) ? suf[t + d] : 0u;
    __syncthreads();
    suf[t] += add;
    __syncthreads();
  }
  unsigned int st = suf[t];
  unsigned int sn = (t < 255) ? suf[t + 1] : 0u;
  if (st >= (unsigned)ktop && sn < (unsigned)ktop) csel_sh = t;   // unique
  __syncthreads();
  if (t == 0){
    int b_sel = 0;
    if (csel_sh >= 0){
      int c = csel_sh;
      unsigned int cum = (c < 255) ? suf[c + 1] : 0u;
      for (int b = 8 * c + 7; b >= 8 * c; --b){
        cum += hist[b];
        if (cum >= (unsigned)ktop){ b_sel = b; break; }
      }
    }
    scal_u[1] = ((unsigned int)b_sel) << 21;
  }
}

// Collect entries >= bin edge (superset of top-ktop); last block does exact
// rank-select, denom, and gumbel-argmax categorical.
__global__ __launch_bounds__(256) void k_collect(const float* __restrict__ scores,
    unsigned int* __restrict__ scal_u, unsigned int* __restrict__ buf_idx,
    float* __restrict__ buf_s, float* __restrict__ out, int N, int ktop){
  int t = threadIdx.x;
  unsigned int u_lo = scal_u[1];
  int i0 = (blockIdx.x * 256 + t) * 4;
  if (i0 + 3 < N){
    float4 s4 = *(const float4*)(scores + i0);
    float ss[4] = {s4.x, s4.y, s4.z, s4.w};
    #pragma unroll
    for (int e = 0; e < 4; ++e){
      float s = ss[e];
      if (s > NEG_INF && f2ord(s) >= u_lo){
        unsigned int pos = atomicAdd(&scal_u[0], 1u);
        if (pos < CAP){ buf_idx[pos] = (unsigned int)(i0 + e); buf_s[pos] = s; }
      }
    }
  } else {
    for (int e = 0; e < 4; ++e){
      int i = i0 + e;
      if (i < N){
        float s = scores[i];
        if (s > NEG_INF && f2ord(s) >= u_lo){
          unsigned int pos = atomicAdd(&scal_u[0], 1u);
          if (pos < CAP){ buf_idx[pos] = (unsigned int)i; buf_s[pos] = s; }
        }
      }
    }
  }
  __syncthreads();
  __shared__ int is_last;
  if (t == 0){
    __threadfence();
    unsigned int old = atomicAdd(&scal_u[7], 1u);
    is_last = (old == gridDim.x - 1u);
  }
  __syncthreads();
  if (!is_last) return;
  __threadfence();
  // ---- exact select + categorical ----
  float* scal_f = (float*)scal_u;
  __shared__ float s_lds[CAP];
  __shared__ float thr_sh;
  __shared__ float wred[4];
  __shared__ float rv[4], rl[4];
  __shared__ unsigned int ri[4];
  int C = (int)scal_u[0]; if (C > CAP) C = CAP;
  for (int j = t; j < C; j += 256) s_lds[j] = buf_s[j];
  if (t == 0) thr_sh = NEG_INF;
  __syncthreads();
  if (C > ktop){
    for (int j = t; j < C; j += 256){
      float sj = s_lds[j];
      int g = 0, e = 0;
      for (int k2 = 0; k2 < C; ++k2){
        float sk = s_lds[k2];
        g += (sk > sj);
        e += (sk == sj);
      }
      if (g < ktop && g + e >= ktop) thr_sh = sj;   // all writers same value
    }
  }
  __syncthreads();
  float s_thr = thr_sh;
  float Z = scal_f[3];
  float part = 0.f;
  for (int j = t; j < C; j += 256){
    float sj = s_lds[j];
    if (sj >= s_thr) part += expf(sj);
  }
  #pragma unroll
  for (int off = 32; off; off >>= 1) part += __shfl_xor(part, off, 64);
  int wave = t >> 6, lane = t & 63;
  if (lane == 0) wred[wave] = part;
  __syncthreads();
  float T = wred[0] + wred[1] + wred[2] + wred[3];
  float D = T + 1e-10f * Z;                 // = Z*(sum_top p + 1e-10)
  float lnD = logf(D);
  if (t == 0){ scal_f[4] = s_thr; scal_f[5] = lnD; }
  float bestv = NEG_INF, bestlogit = NEG_INF;
  unsigned int bestidx = 0xFFFFFFFFu;
  for (int j = t; j < C; j += 256){
    float sj = s_lds[j];
    if (sj >= s_thr){
      unsigned int idx = buf_idx[j];
      float logit = sj - lnD;               // log(filtered)
      float val = logit + gumbel_from_idx(idx);
      if (val > bestv || (val == bestv && idx < bestidx)){
        bestv = val; bestlogit = logit; bestidx = idx;
      }
    }
  }
  #pragma unroll
  for (int off = 32; off; off >>= 1){
    float ov = __shfl_xor(bestv, off, 64);
    float ol = __shfl_xor(bestlogit, off, 64);
    unsigned int oi = (unsigned int)__shfl_xor((int)bestidx, off, 64);
    if (ov > bestv || (ov == bestv && oi < bestidx)){
      bestv = ov; bestlogit = ol; bestidx = oi;
    }
  }
  if (lane == 0){ rv[wave] = bestv; rl[wave] = bestlogit; ri[wave] = bestidx; }
  __syncthreads();
  if (t == 0){
    for (int w = 1; w < 4; ++w){
      if (rv[w] > rv[0] || (rv[w] == rv[0] && ri[w] < ri[0])){
        rv[0] = rv[w]; rl[0] = rl[w]; ri[0] = ri[w];
      }
    }
    out[N] = rl[0];                 // log_prob_action
    out[N + 1] = (float)ri[0];      // action_idx
  }
}

// rewrite scores in-place into log(filtered + 1e-10)
__global__ __launch_bounds__(256) void k_final(float* __restrict__ out,
    const unsigned int* __restrict__ scal_u, int N){
  const float* scal_f = (const float*)scal_u;
  float s_thr = scal_f[4];
  float lnD = scal_f[5];
  const float NLOG = logf(1e-10f);
  int i0 = (blockIdx.x * 256 + threadIdx.x) * 4;
  if (i0 + 3 < N){
    float4 s4 = *(const float4*)(out + i0);
    float4 r;
    r.x = (s4.x >= s_thr) ? logf(expf(s4.x - lnD) + 1e-10f) : NLOG;
    r.y = (s4.y >= s_thr) ? logf(expf(s4.y - lnD) + 1e-10f) : NLOG;
    r.z = (s4.z >= s_thr) ? logf(expf(s4.z - lnD) + 1e-10f) : NLOG;
    r.w = (s4.w >= s_thr) ? logf(expf(s4.w - lnD) + 1e-10f) : NLOG;
    *(float4*)(out + i0) = r;
  } else {
    for (int e = 0; e < 4; ++e){
      int i = i0 + e;
      if (i < N){
        float s = out[i];
        out[i] = (s >= s_thr) ? logf(expf(s - lnD) + 1e-10f) : NLOG;
      }
    }
  }
}

extern "C" void kernel_launch(void* const* d_in, const int* in_sizes, int n_in,
                              void* d_out, int out_size, void* d_ws, size_t ws_size,
                              hipStream_t stream){
  const float* cur  = (const float*)d_in[0];
  const float* ctx  = (const float*)d_in[1];
  const float* cand = (const float*)d_in[2];
  const float* Wq   = (const float*)d_in[3];
  const float* Wk   = (const float*)d_in[4];
  const int*   mask = (const int*)d_in[5];
  int N = in_sizes[5];
  float* out = (float*)d_out;

  char* ws = (char*)d_ws;
  unsigned int* hist    = (unsigned int*)ws;                    // 8192 B
  float*        v       = (float*)(ws + 8192);                  // 512 B
  unsigned int* scal_u  = (unsigned int*)(ws + 8704);           // 32 B (pad 64)
  unsigned int* buf_idx = (unsigned int*)(ws + 8768);           // CAP*4
  float*        buf_s   = (float*)(ws + 8768 + CAP * 4);        // CAP*4

  int ktop = N / 2; if (ktop < 1) ktop = 1; if (ktop > 50) ktop = 50;

  int ntiles = (N + 63) / 64;
  int g_score = ntiles < SCORE_BLOCKS ? ntiles : SCORE_BLOCKS;
  int g_pass  = (N + 1023) / 1024;   // 4 elems/thread

  k_prep<<<1, 256, 0, stream>>>(cur, ctx, Wq, Wk, v, hist, scal_u);
  k_score<<<g_score, 256, 0, stream>>>(cand, mask, v, out, hist, scal_u, N, ktop);
  k_collect<<<g_pass, 256, 0, stream>>>(out, scal_u, buf_idx, buf_s, out, N, ktop);
  k_final<<<g_pass, 256, 0, stream>>>(out, scal_u, N);
}

// Round 5
// 208.861 us; speedup vs baseline: 2.0964x; 1.0527x over previous
//
#include <hip/hip_runtime.h>
#include <math.h>

// AttentionDecoder: score_i = (Wk^T (Wq [cur;ctx])) . cand_i over N=200000,
// masked softmax -> top-50 threshold filter -> renormalize -> log, plus
// bit-exact jax.random.categorical(key(42)) via partitionable-threefry gumbel.
// R5: k_score is a PURE streaming GEMV (no LDS/atomics, 1 tile/block, full
// occupancy, 8 unconditional loads in flight). Histogram+Z move to k_hist
// (0.8MB pass, LDS hist, <=196 same-address flush atomics, scan in last block).
// 5 kernels: prep | score | hist(+scan) | gather(+select+categorical) | final.

#define CAP 4096
#define NEG_INF (-__builtin_inff())

// order-preserving float->uint mapping (monotone increasing)
__device__ __forceinline__ unsigned int f2ord(float f){
  unsigned int b = __float_as_uint(f);
  return (b & 0x80000000u) ? ~b : (b | 0x80000000u);
}
__device__ __forceinline__ unsigned int rotl32(unsigned int x, int d){
  return (x << d) | (x >> (32 - d));
}

// JAX partitionable threefry, key (0,42): x0=idx>>32(=0), x1=idx; bits=w0^w1.
// gumbel = -log(-log(u)), u = bitcast((bits>>9)|0x3f800000)-1 clamped to tiny.
__device__ float gumbel_from_idx(unsigned int idx){
  unsigned int x0 = 0u, x1 = idx;
  const unsigned int ks0 = 0u, ks1 = 42u;
  const unsigned int ks2 = 0u ^ 42u ^ 0x1BD11BDAu;
  x0 += ks0; x1 += ks1;
#define TF_RND(r) { x0 += x1; x1 = rotl32(x1, (r)); x1 ^= x0; }
  TF_RND(13) TF_RND(15) TF_RND(26) TF_RND(6)
  x0 += ks1; x1 += ks2 + 1u;
  TF_RND(17) TF_RND(29) TF_RND(16) TF_RND(24)
  x0 += ks2; x1 += ks0 + 2u;
  TF_RND(13) TF_RND(15) TF_RND(26) TF_RND(6)
  x0 += ks0; x1 += ks1 + 3u;
  TF_RND(17) TF_RND(29) TF_RND(16) TF_RND(24)
  x0 += ks1; x1 += ks2 + 4u;
  TF_RND(13) TF_RND(15) TF_RND(26) TF_RND(6)
  x0 += ks2; x1 += ks0 + 5u;
#undef TF_RND
  unsigned int bits = x0 ^ x1;
  unsigned int fb = (bits >> 9) | 0x3f800000u;
  float f = __uint_as_float(fb) - 1.0f;
  float u = (f < 1.17549435e-38f) ? 1.17549435e-38f : f;
  return -logf(-logf(u));
}

// scal layout (uint/float aliased):
// [0]=nbuf [1]=u_lo [3]=Z [4]=s_thr [5]=lnD [6]=done_hist [7]=done_gather
__global__ void k_prep(const float* __restrict__ cur, const float* __restrict__ ctx,
                       const float* __restrict__ Wq, const float* __restrict__ Wk,
                       float* __restrict__ v, unsigned int* __restrict__ hist,
                       unsigned int* __restrict__ scal_u){
  __shared__ float comb[256];
  __shared__ float q[128];
  int t = threadIdx.x;
  for (int k = t; k < 2048; k += 256) hist[k] = 0u;
  if (t < 8) scal_u[t] = 0u;
  comb[t] = (t < 128) ? cur[t] : ctx[t - 128];
  __syncthreads();
  if (t < 128){
    float acc = 0.f;
    const float* row = Wq + t * 256;
    for (int j = 0; j < 256; ++j) acc = fmaf(row[j], comb[j], acc);
    q[t] = acc;
  }
  __syncthreads();
  if (t < 128){
    float acc = 0.f;
    for (int h = 0; h < 128; ++h) acc = fmaf(q[h], Wk[h * 128 + t], acc);
    v[t] = acc;
  }
}

// Pure GEMV. Half-wave per row (32 lanes x float4 = full 512B row), 16 rows
// per wave, 64 rows per block, one tile per block. Straight-line: all 8 loads
// unconditional (clamped row index) -> compiler keeps them in flight.
__global__ __launch_bounds__(256) void k_score(const float* __restrict__ cand,
    const int* __restrict__ mask, const float* __restrict__ v,
    float* __restrict__ scores, int N){
  int t = threadIdx.x;
  int lane = t & 63, wave = t >> 6;
  int hi = lane >> 5, hl = lane & 31;
  float4 v4 = ((const float4*)v)[hl];
  const float4* cp = (const float4*)cand;
  int base = (blockIdx.x * 4 + wave) * 16;
  float p[8];
  #pragma unroll
  for (int k = 0; k < 8; ++k){
    int r = base + 2 * k + hi;
    r = (r < N) ? r : (N - 1);                 // clamp: load stays unconditional
    float4 c = cp[(size_t)r * 32 + hl];
    p[k] = fmaf(c.x, v4.x, fmaf(c.y, v4.y, fmaf(c.z, v4.z, c.w * v4.w)));
  }
  #pragma unroll
  for (int k = 0; k < 8; ++k){                 // 8 independent 5-shfl chains
    p[k] += __shfl_xor(p[k], 1, 64);
    p[k] += __shfl_xor(p[k], 2, 64);
    p[k] += __shfl_xor(p[k], 4, 64);
    p[k] += __shfl_xor(p[k], 8, 64);
    p[k] += __shfl_xor(p[k], 16, 64);
  }
  float sv = p[0];
  #pragma unroll
  for (int k = 1; k < 8; ++k) sv = (hl == k) ? p[k] : sv;
  if (hl < 8){                                 // writer lanes
    int r = base + 2 * hl + hi;
    if (r < N) scores[r] = mask[r] ? sv : NEG_INF;
  }
}

// 0.8MB pass: LDS histogram + Z over stored scores; flush (<=gridDim atomics
// per address); last block does the suffix scan -> u_lo.
__global__ __launch_bounds__(256) void k_hist(const float* __restrict__ scores,
    unsigned int* __restrict__ hist, unsigned int* __restrict__ scal_u,
    int N, int ktop){
  __shared__ unsigned int lhist[2048];
  __shared__ float wsum[4];
  __shared__ int is_last;
  int t = threadIdx.x;
  int lane = t & 63, wave = t >> 6;
  for (int k = t; k < 2048; k += 256) lhist[k] = 0u;
  __syncthreads();
  float ez = 0.f;
  int i0 = (blockIdx.x * 256 + t) * 4;
  if (i0 + 3 < N){
    float4 s4 = *(const float4*)(scores + i0);
    float ss[4] = {s4.x, s4.y, s4.z, s4.w};
    #pragma unroll
    for (int e = 0; e < 4; ++e){
      if (ss[e] > NEG_INF){
        atomicAdd(&lhist[f2ord(ss[e]) >> 21], 1u);
        ez += expf(ss[e]);                     // |s| bounded ~58: no overflow
      }
    }
  } else {
    for (int e = 0; e < 4; ++e){
      int i = i0 + e;
      if (i < N){
        float s = scores[i];
        if (s > NEG_INF){ atomicAdd(&lhist[f2ord(s) >> 21], 1u); ez += expf(s); }
      }
    }
  }
  #pragma unroll
  for (int off = 32; off; off >>= 1) ez += __shfl_xor(ez, off, 64);
  if (lane == 0) wsum[wave] = ez;
  __syncthreads();
  for (int k = t; k < 2048; k += 256){
    unsigned int c = lhist[k];
    if (c) atomicAdd(&hist[k], c);
  }
  if (t == 0) atomicAdd((float*)scal_u + 3, wsum[0] + wsum[1] + wsum[2] + wsum[3]);
  __syncthreads();
  if (t == 0){
    __threadfence();
    unsigned int old = atomicAdd(&scal_u[6], 1u);
    is_last = (old == gridDim.x - 1u);
  }
  __syncthreads();
  if (!is_last) return;
  __threadfence();
  // ---- histogram suffix scan -> u_lo (bin lower edge of ktop-th score) ----
  __shared__ unsigned int suf[256];
  __shared__ int csel_sh;
  unsigned int csum = 0;
  for (int k = 0; k < 8; ++k) csum += hist[t * 8 + k];
  suf[t] = csum;
  if (t == 0) csel_sh = -1;
  __syncthreads();
  for (int d = 1; d < 256; d <<= 1){
    unsigned int add = (t + d < 256) ? suf[t + d] : 0u;
    __syncthreads();
    suf[t] += add;
    __syncthreads();
  }
  unsigned int st = suf[t];
  unsigned int sn = (t < 255) ? suf[t + 1] : 0u;
  if (st >= (unsigned)ktop && sn < (unsigned)ktop) csel_sh = t;   // unique
  __syncthreads();
  if (t == 0){
    int b_sel = 0;
    if (csel_sh >= 0){
      int c = csel_sh;
      unsigned int cum = (c < 255) ? suf[c + 1] : 0u;
      for (int b = 8 * c + 7; b >= 8 * c; --b){
        cum += hist[b];
        if (cum >= (unsigned)ktop){ b_sel = b; break; }
      }
    }
    scal_u[1] = ((unsigned int)b_sel) << 21;
  }
}

// Gather entries >= bin edge (superset of top-ktop); last block does exact
// rank-select, denom, and gumbel-argmax categorical.
__global__ __launch_bounds__(256) void k_gather(const float* __restrict__ scores,
    unsigned int* __restrict__ scal_u, unsigned int* __restrict__ buf_idx,
    float* __restrict__ buf_s, float* __restrict__ out, int N, int ktop){
  int t = threadIdx.x;
  unsigned int u_lo = scal_u[1];
  int i0 = (blockIdx.x * 256 + t) * 4;
  if (i0 + 3 < N){
    float4 s4 = *(const float4*)(scores + i0);
    float ss[4] = {s4.x, s4.y, s4.z, s4.w};
    #pragma unroll
    for (int e = 0; e < 4; ++e){
      float s = ss[e];
      if (s > NEG_INF && f2ord(s) >= u_lo){
        unsigned int pos = atomicAdd(&scal_u[0], 1u);
        if (pos < CAP){ buf_idx[pos] = (unsigned int)(i0 + e); buf_s[pos] = s; }
      }
    }
  } else {
    for (int e = 0; e < 4; ++e){
      int i = i0 + e;
      if (i < N){
        float s = scores[i];
        if (s > NEG_INF && f2ord(s) >= u_lo){
          unsigned int pos = atomicAdd(&scal_u[0], 1u);
          if (pos < CAP){ buf_idx[pos] = (unsigned int)i; buf_s[pos] = s; }
        }
      }
    }
  }
  __syncthreads();
  __shared__ int is_last;
  if (t == 0){
    __threadfence();
    unsigned int old = atomicAdd(&scal_u[7], 1u);
    is_last = (old == gridDim.x - 1u);
  }
  __syncthreads();
  if (!is_last) return;
  __threadfence();
  // ---- exact select + categorical ----
  float* scal_f = (float*)scal_u;
  __shared__ float s_lds[CAP];
  __shared__ float thr_sh;
  __shared__ float wred[4];
  __shared__ float rv[4], rl[4];
  __shared__ unsigned int ri[4];
  int C = (int)scal_u[0]; if (C > CAP) C = CAP;
  for (int j = t; j < C; j += 256) s_lds[j] = buf_s[j];
  if (t == 0) thr_sh = NEG_INF;
  __syncthreads();
  if (C > ktop){
    for (int j = t; j < C; j += 256){
      float sj = s_lds[j];
      int g = 0, e = 0;
      for (int k2 = 0; k2 < C; ++k2){
        float sk = s_lds[k2];
        g += (sk > sj);
        e += (sk == sj);
      }
      if (g < ktop && g + e >= ktop) thr_sh = sj;   // all writers same value
    }
  }
  __syncthreads();
  float s_thr = thr_sh;
  float Z = scal_f[3];
  float part = 0.f;
  for (int j = t; j < C; j += 256){
    float sj = s_lds[j];
    if (sj >= s_thr) part += expf(sj);
  }
  #pragma unroll
  for (int off = 32; off; off >>= 1) part += __shfl_xor(part, off, 64);
  int wave = t >> 6, lane = t & 63;
  if (lane == 0) wred[wave] = part;
  __syncthreads();
  float T = wred[0] + wred[1] + wred[2] + wred[3];
  float D = T + 1e-10f * Z;                 // = Z*(sum_top p + 1e-10)
  float lnD = logf(D);
  if (t == 0){ scal_f[4] = s_thr; scal_f[5] = lnD; }
  float bestv = NEG_INF, bestlogit = NEG_INF;
  unsigned int bestidx = 0xFFFFFFFFu;
  for (int j = t; j < C; j += 256){
    float sj = s_lds[j];
    if (sj >= s_thr){
      unsigned int idx = buf_idx[j];
      float logit = sj - lnD;               // log(filtered)
      float val = logit + gumbel_from_idx(idx);
      if (val > bestv || (val == bestv && idx < bestidx)){
        bestv = val; bestlogit = logit; bestidx = idx;
      }
    }
  }
  #pragma unroll
  for (int off = 32; off; off >>= 1){
    float ov = __shfl_xor(bestv, off, 64);
    float ol = __shfl_xor(bestlogit, off, 64);
    unsigned int oi = (unsigned int)__shfl_xor((int)bestidx, off, 64);
    if (ov > bestv || (ov == bestv && oi < bestidx)){
      bestv = ov; bestlogit = ol; bestidx = oi;
    }
  }
  if (lane == 0){ rv[wave] = bestv; rl[wave] = bestlogit; ri[wave] = bestidx; }
  __syncthreads();
  if (t == 0){
    for (int w = 1; w < 4; ++w){
      if (rv[w] > rv[0] || (rv[w] == rv[0] && ri[w] < ri[0])){
        rv[0] = rv[w]; rl[0] = rl[w]; ri[0] = ri[w];
      }
    }
    out[N] = rl[0];                 // log_prob_action
    out[N + 1] = (float)ri[0];      // action_idx
  }
}

// rewrite scores in-place into log(filtered + 1e-10)
__global__ __launch_bounds__(256) void k_final(float* __restrict__ out,
    const unsigned int* __restrict__ scal_u, int N){
  const float* scal_f = (const float*)scal_u;
  float s_thr = scal_f[4];
  float lnD = scal_f[5];
  const float NLOG = logf(1e-10f);
  int i0 = (blockIdx.x * 256 + threadIdx.x) * 4;
  if (i0 + 3 < N){
    float4 s4 = *(const float4*)(out + i0);
    float4 r;
    r.x = (s4.x >= s_thr) ? logf(expf(s4.x - lnD) + 1e-10f) : NLOG;
    r.y = (s4.y >= s_thr) ? logf(expf(s4.y - lnD) + 1e-10f) : NLOG;
    r.z = (s4.z >= s_thr) ? logf(expf(s4.z - lnD) + 1e-10f) : NLOG;
    r.w = (s4.w >= s_thr) ? logf(expf(s4.w - lnD) + 1e-10f) : NLOG;
    *(float4*)(out + i0) = r;
  } else {
    for (int e = 0; e < 4; ++e){
      int i = i0 + e;
      if (i < N){
        float s = out[i];
        out[i] = (s >= s_thr) ? logf(expf(s - lnD) + 1e-10f) : NLOG;
      }
    }
  }
}

extern "C" void kernel_launch(void* const* d_in, const int* in_sizes, int n_in,
                              void* d_out, int out_size, void* d_ws, size_t ws_size,
                              hipStream_t stream){
  const float* cur  = (const float*)d_in[0];
  const float* ctx  = (const float*)d_in[1];
  const float* cand = (const float*)d_in[2];
  const float* Wq   = (const float*)d_in[3];
  const float* Wk   = (const float*)d_in[4];
  const int*   mask = (const int*)d_in[5];
  int N = in_sizes[5];
  float* out = (float*)d_out;

  char* ws = (char*)d_ws;
  unsigned int* hist    = (unsigned int*)ws;                    // 8192 B
  float*        v       = (float*)(ws + 8192);                  // 512 B
  unsigned int* scal_u  = (unsigned int*)(ws + 8704);           // 32 B (pad 64)
  unsigned int* buf_idx = (unsigned int*)(ws + 8768);           // CAP*4
  float*        buf_s   = (float*)(ws + 8768 + CAP * 4);        // CAP*4

  int ktop = N / 2; if (ktop < 1) ktop = 1; if (ktop > 50) ktop = 50;

  int g_score = (N + 63) / 64;       // one 64-row tile per block
  int g_pass  = (N + 1023) / 1024;   // 4 elems/thread

  k_prep<<<1, 256, 0, stream>>>(cur, ctx, Wq, Wk, v, hist, scal_u);
  k_score<<<g_score, 256, 0, stream>>>(cand, mask, v, out, N);
  k_hist<<<g_pass, 256, 0, stream>>>(out, hist, scal_u, N, ktop);
  k_gather<<<g_pass, 256, 0, stream>>>(out, scal_u, buf_idx, buf_s, out, N, ktop);
  k_final<<<g_pass, 256, 0, stream>>>(out, scal_u, N);
}